// Round 14
// baseline (7092.292 us; speedup 1.0000x reference)
//
#include <hip/hip_runtime.h>
#include <stdint.h>
#include <stddef.h>

// ---------------------------------------------------------------------------
// PCgraph: T=32 steps of
//   mu = tanh(x) @ w^T ; e = (x-mu)*m ; g = e @ w ;
//   x = x - 0.1*m*(e - (1-tanh(x)^2)*g)
// bf16 MFMA 16x16x32, fp32 accum. x state in d_out (fp32).
// Round 14: FUSED SPLIT-K REDUCTION (2 dispatches/step, was 4). r10-r13
// showed gemm-side tweaks are sub-dominant to ~20us/step of inter-dispatch
// overhead (gaps + ramps of 4 dispatches + cvt partial traffic). Now each
// gemm block: store bf16 partial -> __threadfence -> atomicAdd(cnt[tile]);
// the last of Z blocks per 128x128 tile does the reduction + elementwise
// epilogue inline (phase1: e->e_pk; phase2: x update + tanh->t_pk) and
// resets the counter. GEMM core = r13 (128x128, BK=64, packed operands,
// 8 x 1KB-linear DMAs/wave/iter). Z=8 cnt at ws 66,846,720 (+512 needed;
// ws proven >= 66,846,720 by r10-13, almost surely 64 MiB); Z=4 fallback.
// ---------------------------------------------------------------------------

#define N_DIM 4096
#define B_DIM 256
#define T_STEPS 32
#define LR_X 0.1f
#define N0 768                      // first live column (aligned down from 784)
#define N_LIVE 3328                 // 4096 - 768 = 52*64

#define NCH1 64                     // 64-wide k-chunks in GEMM1 (k over 4096)
#define NCH2 52                     // k-chunks in GEMM2 (k over 3328)

typedef unsigned short ushort_t;
using bf16x8 = __attribute__((ext_vector_type(8))) __bf16;
using f32x4  = __attribute__((ext_vector_type(4))) float;

__device__ __forceinline__ ushort_t f2bf(float f) {
    union { float f; unsigned int u; } v; v.f = f;
    unsigned int r = v.u + 0x7fffu + ((v.u >> 16) & 1u);   // RNE
    return (ushort_t)(r >> 16);
}
__device__ __forceinline__ float bf2f(ushort_t h) {
    union { unsigned int u; float f; } v; v.u = ((unsigned int)h) << 16;
    return v.f;
}

// fragment-order index of element (r, c) inside a 64x64 tile-chunk
__device__ __forceinline__ int pkidx(int r, int c) {
    const int s = ((r >> 4) << 1) | ((c >> 5) & 1);
    return s * 512 + (r & 15) * 8 + (((c >> 3) & 3) << 7) + (c & 7);
}

__device__ __forceinline__ void async_copy16(const ushort_t* g, ushort_t* l) {
    __builtin_amdgcn_global_load_lds(
        (__attribute__((address_space(1))) void*)(g),
        (__attribute__((address_space(3))) void*)(l),
        16, 0, 0);
}

// --- pack w -> w_pk [52 ntile][64 chunk][4096]  (B of GEMM1: rows 768..4095)
//            -> wt_pk [52 ntile][52 chunk][4096] (B of GEMM2: w^T, live range)
//     + zero the 52 tile counters (block 0)
__global__ __launch_bounds__(256) void pack_w(const float* __restrict__ w,
                                              ushort_t* __restrict__ wpk,
                                              ushort_t* __restrict__ wtpk,
                                              int* __restrict__ cnt) {
    if (blockIdx.x == 0 && threadIdx.x < 64) cnt[threadIdx.x] = 0;
    __shared__ float tile[64][68];
    const int tid = threadIdx.x;
    const int bid = blockIdx.x;
    int row0, col0; ushort_t* dst; bool tr;
    if (bid < 52 * 64) {
        tr   = false;
        dst  = wpk + (size_t)bid * 4096;
        row0 = N0 + (bid >> 6) * 64;      // B-row (n) block
        col0 = (bid & 63) * 64;           // k block
    } else {
        const int b2 = bid - 52 * 64;
        tr   = true;
        dst  = wtpk + (size_t)b2 * 4096;
        const int ntile = b2 / 52, chunk = b2 - ntile * 52;
        row0 = N0 + chunk * 64;           // w-row  = k block (live)
        col0 = N0 + ntile * 64;           // w-col  = n block (live)
    }
    const int rr = tid >> 2, c0 = (tid & 3) * 16;
    const float* src = w + (size_t)(row0 + rr) * N_DIM + col0 + c0;
#pragma unroll
    for (int i = 0; i < 16; i += 4)
        *(float4*)&tile[rr][c0 + i] = *(const float4*)(src + i);
    __syncthreads();
    ushort_t loc[16];
#pragma unroll
    for (int i = 0; i < 16; ++i) {
        const int p = tid * 16 + i;
        const int s = p >> 9, e = p & 511;
        const int r = ((s >> 1) << 4) | ((e >> 3) & 15);
        const int c = ((s & 1) << 5) | (((e >> 7) & 3) << 3) | (e & 7);
        loc[i] = f2bf(tr ? tile[c][r] : tile[r][c]);
    }
    *(uint4*)&dst[tid * 16]     = *(uint4*)&loc[0];
    *(uint4*)&dst[tid * 16 + 8] = *(uint4*)&loc[8];
}

// --- init: x -> d_out (row-major) and t_pk [4 mtile][64 chunk][4096] --------
__global__ __launch_bounds__(256) void pack_t_init(const float* __restrict__ xin,
                                                   float* __restrict__ xout,
                                                   ushort_t* __restrict__ tpk) {
    __shared__ float tile[64][68];
    const int tid  = threadIdx.x;
    const int bid  = blockIdx.x;          // mtile*64 + chunk
    const int row0 = (bid >> 6) * 64;
    const int col0 = (bid & 63) * 64;
    const int rr = tid >> 2, c0 = (tid & 3) * 16;
    const size_t sidx = (size_t)(row0 + rr) * N_DIM + col0 + c0;
#pragma unroll
    for (int i = 0; i < 16; i += 4) {
        float4 v = *(const float4*)(xin + sidx + i);
        *(float4*)(xout + sidx + i) = v;
        tile[rr][c0 + i + 0] = tanhf(v.x);
        tile[rr][c0 + i + 1] = tanhf(v.y);
        tile[rr][c0 + i + 2] = tanhf(v.z);
        tile[rr][c0 + i + 3] = tanhf(v.w);
    }
    __syncthreads();
    ushort_t loc[16];
    ushort_t* dst = tpk + (size_t)bid * 4096;
#pragma unroll
    for (int i = 0; i < 16; ++i) {
        const int p = tid * 16 + i;
        const int s = p >> 9, e = p & 511;
        const int r = ((s >> 1) << 4) | ((e >> 3) & 15);
        const int c = ((s & 1) << 5) | (((e >> 7) & 3) << 3) | (e & 7);
        loc[i] = f2bf(tile[r][c]);
    }
    *(uint4*)&dst[tid * 16]     = *(uint4*)&loc[0];
    *(uint4*)&dst[tid * 16 + 8] = *(uint4*)&loc[8];
}

// --- split-K GEMM + fused last-block reduction ------------------------------
// grid (26, 2, Z). 128x128 tile, BK=64 (full packed chunk/iter), 64 KB LDS.
// PHASE 1 reduction: mu = sum part; e = (x-mu)*m -> e_pk (packed, GEMM2 A)
// PHASE 2 reduction: g = sum part; x -= lr*m*(e-(1-th^2)g); t_pk = tanh(x)
template <int PHASE, int NCH, int Z>
__global__ __launch_bounds__(256) void gemm_step(
    const ushort_t* __restrict__ Apk,
    const ushort_t* __restrict__ Bpk,
    ushort_t* __restrict__ part,
    float* xbuf,
    ushort_t* epk,
    ushort_t* tpk,
    const int* __restrict__ mask,
    int* __restrict__ cnt) {
    __shared__ __align__(16) ushort_t As[2][16 * 512];  // 2 x 16 KB
    __shared__ __align__(16) ushort_t Bs[2][16 * 512];  // 2 x 16 KB
    __shared__ int s_last;

    const int tid    = threadIdx.x;
    const int lane   = tid & 63;
    const int wid    = tid >> 6;       // 0..3
    const int wave_m = wid >> 1;       // 0..1  (64-row half of 128)
    const int wave_n = wid & 1;        // 0..1  (64-col half of 128)
    const int ntile2 = blockIdx.x;     // covers ntiles {2x, 2x+1}
    const int mtile2 = blockIdx.y;     // covers mtiles {2y, 2y+1}
    const int z      = blockIdx.z;

    const int per = NCH / Z, rem = NCH % Z;
    const int kcount = per + (z < rem ? 1 : 0);
    const int kstart = z * per + (z < rem ? z : rem);
    ushort_t* pout = part + (size_t)z * (B_DIM * N_LIVE);

    const int l15  = lane & 15;
    const int quad = lane >> 4;        // 0..3

    const ushort_t* Ab0 = Apk + ((size_t)(mtile2 * 2) * NCH + kstart) * 4096;
    const ushort_t* Ab1 = Ab0 + (size_t)NCH * 4096;
    const ushort_t* Bb0 = Bpk + ((size_t)(ntile2 * 2) * NCH + kstart) * 4096;
    const ushort_t* Bb1 = Bb0 + (size_t)NCH * 4096;

    auto stage = [&](int buf, int kt) {
        const size_t co = (size_t)kt * 4096;
#pragma unroll
        for (int u = 0; u < 4; ++u) {
            const int st  = wid * 4 + u;             // 0..15
            const int so  = (st & 7) * 512 + lane * 8;
            const int dof = st * 512 + lane * 8;
            async_copy16((st < 8 ? Ab0 : Ab1) + co + so, &As[buf][dof]);
            async_copy16((st < 8 ? Bb0 : Bb1) + co + so, &Bs[buf][dof]);
        }
    };

    f32x4 acc[4][4] = {};

    auto compute = [&](int buf) {
#pragma unroll
        for (int ks = 0; ks < 2; ++ks) {
            bf16x8 a[4], b[4];
#pragma unroll
            for (int i = 0; i < 4; ++i)
                a[i] = *(const bf16x8*)(
                    &As[buf][(wave_m * 8 + i * 2 + ks) * 512 + lane * 8]);
#pragma unroll
            for (int j = 0; j < 4; ++j)
                b[j] = *(const bf16x8*)(
                    &Bs[buf][(wave_n * 8 + j * 2 + ks) * 512 + lane * 8]);
#pragma unroll
            for (int i = 0; i < 4; ++i)
#pragma unroll
                for (int j = 0; j < 4; ++j)
                    acc[i][j] = __builtin_amdgcn_mfma_f32_16x16x32_bf16(
                        a[i], b[j], acc[i][j], 0, 0, 0);
        }
    };

    stage(0, 0);
    __syncthreads();
    for (int kt = 0; kt < kcount; ++kt) {
        if (kt + 1 < kcount) stage((kt + 1) & 1, kt + 1);
        compute(kt & 1);
        __syncthreads();
    }

    // Partial store. C/D layout: col = lane&15, row = quad*4+reg
#pragma unroll
    for (int j = 0; j < 4; ++j) {
        const int nl = ntile2 * 128 + wave_n * 64 + j * 16 + l15;
#pragma unroll
        for (int i = 0; i < 4; ++i) {
#pragma unroll
            for (int r = 0; r < 4; ++r) {
                const int m = mtile2 * 128 + wave_m * 64 + i * 16 + quad * 4 + r;
                pout[(size_t)m * N_LIVE + nl] = f2bf(acc[i][j][r]);
            }
        }
    }

    // Last-of-Z detection (release my stores, then count).
    __threadfence();
    __syncthreads();
    if (tid == 0) {
        const int tileid = mtile2 * 26 + ntile2;
        const int old = atomicAdd(&cnt[tileid], 1);
        s_last = (old == Z - 1) ? 1 : 0;
        if (s_last) cnt[tileid] = 0;     // reset for next dispatch
    }
    __syncthreads();
    if (!s_last) return;
    __threadfence();                      // acquire side before partial reads

    // Reduction + elementwise epilogue for this 128x128 region.
    const int m0r = mtile2 * 128;
    const int nl0 = ntile2 * 128;
    for (int it = 0; it < 64; ++it) {
        const int idx = it * 256 + tid;   // 0..16383
        const int r   = idx >> 7;         // 0..127
        const int c   = idx & 127;
        const int mr  = m0r + r;
        const int nl  = nl0 + c;
        const size_t il = (size_t)mr * N_LIVE + nl;
        float s = 0.0f;
#pragma unroll
        for (int z2 = 0; z2 < Z; ++z2)
            s += bf2f(part[(size_t)z2 * (B_DIM * N_LIVE) + il]);
        const size_t ix = (size_t)mr * N_DIM + N0 + nl;
        const float mv = (float)mask[N0 + nl];
        const size_t ei = ((size_t)((mr >> 6) * NCH2 + (nl >> 6))) * 4096
                        + pkidx(mr & 63, nl & 63);
        if (PHASE == 1) {
            const float e = (xbuf[ix] - s) * mv;
            epk[ei] = f2bf(e);
        } else {
            const float x  = xbuf[ix];
            const float th = tanhf(x);
            const float e  = bf2f(epk[ei]);
            const float xn = x - LR_X * mv * (e - (1.0f - th * th) * s);
            xbuf[ix] = xn;
            const int k = N0 + nl;
            tpk[((size_t)((mr >> 6) * NCH1 + (k >> 6))) * 4096
                + pkidx(mr & 63, k & 63)] = f2bf(tanhf(xn));
        }
    }
}

extern "C" void kernel_launch(void* const* d_in, const int* in_sizes, int n_in,
                              void* d_out, int out_size, void* d_ws, size_t ws_size,
                              hipStream_t stream) {
    const float* x_in  = (const float*)d_in[0];
    const float* w_in  = (const float*)d_in[1];
    const int*   mask  = (const int*)d_in[2];
    float*       xbuf  = (float*)d_out;          // state lives in d_out

    uint8_t* ws = (uint8_t*)d_ws;
    ushort_t* w_pk  = (ushort_t*)(ws);                   // 52*64*4096*2 = 27,262,976
    ushort_t* wt_pk = (ushort_t*)(ws + 27262976);        // 52*52*4096*2 = 22,151,168
    ushort_t* t_pk  = (ushort_t*)(ws + 49414144);        //  4*64*4096*2 =  2,097,152
    ushort_t* e_pk  = (ushort_t*)(ws + 51511296);        //  4*52*4096*2 =  1,703,936
    ushort_t* part  = (ushort_t*)(ws + 53215232);        // Z*256*3328*2

    // Z=8: partials end @ 66,846,720 (proven in-bounds r10-13) + 256B counters.
    const int Z = (ws_size >= (size_t)(66846720 + 512)) ? 8 : 4;
    int* cnt = (int*)(ws + (Z == 8 ? (size_t)66846720 : (size_t)60030976));

    pack_w<<<dim3(52 * 64 + 52 * 52), 256, 0, stream>>>(w_in, w_pk, wt_pk, cnt);
    pack_t_init<<<dim3(4 * 64), 256, 0, stream>>>(x_in, xbuf, t_pk);

    const dim3 ggrid(N_LIVE / 128, B_DIM / 128, Z);
    for (int t = 0; t < T_STEPS; ++t) {
        if (Z == 8) {
            gemm_step<1, NCH1, 8><<<ggrid, 256, 0, stream>>>(
                t_pk, w_pk, part, xbuf, e_pk, t_pk, mask, cnt);
            gemm_step<2, NCH2, 8><<<ggrid, 256, 0, stream>>>(
                e_pk, wt_pk, part, xbuf, e_pk, t_pk, mask, cnt);
        } else {
            gemm_step<1, NCH1, 4><<<ggrid, 256, 0, stream>>>(
                t_pk, w_pk, part, xbuf, e_pk, t_pk, mask, cnt);
            gemm_step<2, NCH2, 4><<<ggrid, 256, 0, stream>>>(
                e_pk, wt_pk, part, xbuf, e_pk, t_pk, mask, cnt);
        }
    }
}